// Round 10
// baseline (249.695 us; speedup 1.0000x reference)
//
// Round 10: r9 with ONE change — y-halo restored 4->6 (SH 24->28). r9's
// gather->LDS conversion was clean (no spill) but traded halo size down,
// raising the per-wave probability of the divergent 20-load global-fallback
// path from ~1.5% to tens of percent (P(|fay|>4)~1%/lane x 64 lanes).
// Restoring HSY=6 makes ~98.5% of waves pure-LDS. LDS 44.8KB -> 3 blocks/CU;
// occupancy proven not a lever for this kernel (r1/r2: 31-72% same time).
// Bitwise-identical output. dirB/flows/finalize unchanged (r4).
#include <hip/hip_runtime.h>
#include <math.h>

#define BATCH 8
#define IH 384
#define IW 512
#define NPIX (IH*IW)          // 196608
#define BN (BATCH*NPIX)       // 1572864

#define TW 64
#define TH 16
#define RW (TW+4)             // 68
#define RH (TH+4)             // 20
#define NTX (IW/TW)           // 8
#define NTY (IH/TH)           // 24
#define NZ  (BATCH*2)         // 16
#define NB_DIR (NTX*NTY*NZ)   // 3072

// staging window: tile + halo (x:8, y:6); 5 channels (img_b x3, flow_b x2).
// dynamic per-pixel window test with exact global fallback keeps correctness.
#define HSX 8
#define HSY 6
#define SH (TH+2*HSY)         // 28
#define SW (TW+2*HSX)         // 80
#define SF4 (SW/4)            // 20
#define NCH 5

#define NITER_A 4             // 1024/256

#define NB_FLOW 1536
#define PA_OFF 0
#define PB_OFF NB_DIR                  // 3072
#define ENT_OFF (2*NB_DIR)             // 6144
#define EPE_OFF (ENT_OFF + NB_FLOW)    // 7680
#define PART_FLOATS 16384

__device__ __forceinline__ float frcp_(float x){ return __builtin_amdgcn_rcpf(x); }
__device__ __forceinline__ float fsqrt_(float x){ return __builtin_amdgcn_sqrtf(x); }
__device__ __forceinline__ float sigmoidf_(float x){ return frcp_(1.0f + __expf(-x)); }

__device__ __forceinline__ float block_reduce_sum(float v){
    __shared__ float s[8];
    #pragma unroll
    for (int off=32; off>0; off>>=1) v += __shfl_down(v, off);
    int lane = threadIdx.x & 63, wid = threadIdx.x >> 6;
    if (lane==0) s[wid] = v;
    __syncthreads();
    float t = 0.f;
    if (wid==0){
        int nw = (blockDim.x+63)>>6;
        t = (lane < nw) ? s[lane] : 0.f;
        #pragma unroll
        for (int off=4; off>0; off>>=1) t += __shfl_down(t, off);
    }
    __syncthreads();
    return t;
}

// Kernel 1 (r4): flows = mean + exp(lv/2)*noise, PLANAR; entropy+epe partials.
__global__ __launch_bounds__(256)
void flows_kernel(const float* __restrict__ meanf, const float* __restrict__ log_varf,
                  const float* __restrict__ meanb, const float* __restrict__ log_varb,
                  const float* __restrict__ target,
                  const float* __restrict__ noise_f, const float* __restrict__ noise_b,
                  float* __restrict__ flowf, float* __restrict__ flowb,
                  float* __restrict__ part)
{
    int t = blockIdx.x*blockDim.x + threadIdx.x;
    if (t < NB_DIR) part[PB_OFF + t] = 0.f;
    const int NP4 = NPIX/4;
    int b = t / NP4, p4 = t - b*NP4;
    size_t i0 = ((size_t)b*2*NPIX)/4 + p4;
    size_t i1 = i0 + NPIX/4;

    const float4* mf = (const float4*)meanf;  const float4* lf = (const float4*)log_varf;
    const float4* mb = (const float4*)meanb;  const float4* lb = (const float4*)log_varb;
    const float4* nf = (const float4*)noise_f; const float4* nb = (const float4*)noise_b;
    const float4* tg = (const float4*)target;
    float4* ff = (float4*)flowf; float4* fbp = (float4*)flowb;

    float4 lf0 = lf[i0], lf1 = lf[i1], lb0 = lb[i0], lb1 = lb[i1];
    float4 mf0 = mf[i0], mf1 = mf[i1], mb0 = mb[i0], mb1 = mb[i1];
    float4 nf0 = nf[i0], nf1 = nf[i1], nb0 = nb[i0], nb1 = nb[i1];

    float4 o;
    o.x = mf0.x + __expf(0.5f*lf0.x)*nf0.x; o.y = mf0.y + __expf(0.5f*lf0.y)*nf0.y;
    o.z = mf0.z + __expf(0.5f*lf0.z)*nf0.z; o.w = mf0.w + __expf(0.5f*lf0.w)*nf0.w;
    ff[i0] = o;
    o.x = mf1.x + __expf(0.5f*lf1.x)*nf1.x; o.y = mf1.y + __expf(0.5f*lf1.y)*nf1.y;
    o.z = mf1.z + __expf(0.5f*lf1.z)*nf1.z; o.w = mf1.w + __expf(0.5f*lf1.w)*nf1.w;
    ff[i1] = o;
    o.x = mb0.x + __expf(0.5f*lb0.x)*nb0.x; o.y = mb0.y + __expf(0.5f*lb0.y)*nb0.y;
    o.z = mb0.z + __expf(0.5f*lb0.z)*nb0.z; o.w = mb0.w + __expf(0.5f*lb0.w)*nb0.w;
    fbp[i0] = o;
    o.x = mb1.x + __expf(0.5f*lb1.x)*nb1.x; o.y = mb1.y + __expf(0.5f*lb1.y)*nb1.y;
    o.z = mb1.z + __expf(0.5f*lb1.z)*nb1.z; o.w = mb1.w + __expf(0.5f*lb1.w)*nb1.w;
    fbp[i1] = o;

    float ent = (lf0.x+lf0.y+lf0.z+lf0.w) + (lf1.x+lf1.y+lf1.z+lf1.w)
              + (lb0.x+lb0.y+lb0.z+lb0.w) + (lb1.x+lb1.y+lb1.z+lb1.w);

    float4 t0 = tg[i0], t1 = tg[i1];
    float d0, d1, epe = 0.f;
    d0 = mf0.x - t0.x; d1 = mf1.x - t1.x; epe += fsqrt_(d0*d0 + d1*d1);
    d0 = mf0.y - t0.y; d1 = mf1.y - t1.y; epe += fsqrt_(d0*d0 + d1*d1);
    d0 = mf0.z - t0.z; d1 = mf1.z - t1.z; epe += fsqrt_(d0*d0 + d1*d1);
    d0 = mf0.w - t0.w; d1 = mf1.w - t1.w; epe += fsqrt_(d0*d0 + d1*d1);

    float s = block_reduce_sum(ent);
    if (threadIdx.x == 0) part[ENT_OFF + blockIdx.x] = s;
    float s2 = block_reduce_sum(epe);
    if (threadIdx.x == 0) part[EPE_OFF + blockIdx.x] = s2;
}

// ---------------------------------------------------------------------------
// dirA: r4 semantics; img_b (3ch) + flow_b (2ch) staged in one LDS window.
// ---------------------------------------------------------------------------
__global__ __launch_bounds__(256, 3)
void dirA_kernel(const float* __restrict__ flowf, const float* __restrict__ flowb,
                 const float* __restrict__ img1, const float* __restrict__ img2,
                 float* __restrict__ wimg, float* __restrict__ maskbuf,
                 float* __restrict__ part)
{
    __shared__ float sib[NCH][SH][SW];   // ch0-2: img_b, ch3-4: flow_b (0 outside)

    const int z = blockIdx.z;
    const int dir = z & 1, b = z >> 1;
    const float *pfa, *pfb, *pia, *pib;
    if (dir == 0){ pfa = flowf; pfb = flowb; pia = img1; pib = img2; }
    else         { pfa = flowb; pfb = flowf; pia = img2; pib = img1; }
    pfa += (size_t)b*2*NPIX; pfb += (size_t)b*2*NPIX;
    pia += (size_t)b*3*NPIX; pib += (size_t)b*3*NPIX;

    float* wout = wimg + (size_t)z*3*NPIX;
    float* mout = maskbuf + (size_t)z*NPIX;

    const int tw0 = blockIdx.x*TW, th0 = blockIdx.y*TH;
    const int tid = threadIdx.x;
    float local = 0.f;

    // ---- stage img_b + flow_b window (float4; HSX%4==0 so no straddle) ----
    for (int i = tid; i < NCH*SH*SF4; i += 256){
        int c = i / (SH*SF4);
        int rem = i - c*(SH*SF4);
        int r = rem / SF4, c4 = rem - r*SF4;
        int gy = th0 - HSY + r;
        int gx = tw0 - HSX + 4*c4;
        float4 v = make_float4(0.f, 0.f, 0.f, 0.f);
        if (gy >= 0 && gy < IH && gx >= 0 && gx < IW){
            const float* src = (c < 3) ? (pib + (size_t)c*NPIX)
                                       : (pfb + (size_t)(c-3)*NPIX);
            v = *(const float4*)(src + gy*IW + gx);
        }
        *(float4*)&sib[c][r][4*c4] = v;
    }

    // ---- flow_a preload ----
    float rfax[NITER_A], rfay[NITER_A];
    #pragma unroll
    for (int it = 0; it < NITER_A; ++it){
        int i = tid + it*256;
        int hh = i >> 6, ww = i & 63;
        int p = (th0 + hh)*IW + (tw0 + ww);
        rfax[it] = pfa[p];
        rfay[it] = pfa[NPIX + p];
    }
    __syncthreads();

    // ---- warp + terms ----
    #pragma unroll
    for (int it = 0; it < NITER_A; ++it){
        int i = tid + it*256;
        int hh = i >> 6, ww = i & 63;
        int gh = th0 + hh, gw = tw0 + ww;
        int p = gh*IW + gw;
        float fax = rfax[it], fay = rfay[it];
        float Xp = (float)gw + fax;
        float Yp = (float)gh + fay;

        float x0f = floorf(Xp), y0f = floorf(Yp);
        float wx1 = Xp - x0f, wy1 = Yp - y0f;
        float wx0 = 1.f - wx1, wy0 = 1.f - wy1;

        float x1f = x0f + 1.f, y1f = y0f + 1.f;
        bool vx0 = (x0f >= 0.f) && (x0f <= (float)(IW-1));
        bool vx1 = (x1f >= 0.f) && (x1f <= (float)(IW-1));
        bool vy0 = (y0f >= 0.f) && (y0f <= (float)(IH-1));
        bool vy1 = (y1f >= 0.f) && (y1f <= (float)(IH-1));
        float xc0 = fminf(fmaxf(x0f, 0.f), (float)(IW-1));
        float xc1 = fminf(fmaxf(x1f, 0.f), (float)(IW-1));
        float yc0 = fminf(fmaxf(y0f, 0.f), (float)(IH-1));
        float yc1 = fminf(fmaxf(y1f, 0.f), (float)(IH-1));
        int ix0 = (int)xc0, ix1 = (int)xc1, iy0 = (int)yc0, iy1 = (int)yc1;
        int idx0 = iy0*IW + ix0, idx1 = iy0*IW + ix1;
        int idx2 = iy1*IW + ix0, idx3 = iy1*IW + ix1;
        float wt0 = (vx0 && vy0) ? wx0*wy0 : 0.f;
        float wt1 = (vx1 && vy0) ? wx1*wy0 : 0.f;
        float wt2 = (vx0 && vy1) ? wx0*wy1 : 0.f;
        float wt3 = (vx1 && vy1) ? wx1*wy1 : 0.f;

        // warp img_b (3 ch) + flow_b (2 ch): LDS window if all taps inside
        float w0, w1, w2, fbwx, fbwy;
        int lx0 = ix0 - (tw0 - HSX), ly0 = iy0 - (th0 - HSY);
        int lx1 = ix1 - (tw0 - HSX), ly1 = iy1 - (th0 - HSY);
        bool inwin = (lx0 >= 0) && (lx1 < SW) && (ly0 >= 0) && (ly1 < SH);
        if (inwin){
            int o00 = ly0*SW + lx0, o01 = ly0*SW + lx1;
            int o10 = ly1*SW + lx0, o11 = ly1*SW + lx1;
            const float* s0 = &sib[0][0][0];
            const float* s1 = s0 + SH*SW;
            const float* s2 = s1 + SH*SW;
            const float* s3 = s2 + SH*SW;
            const float* s4 = s3 + SH*SW;
            w0   = wt0*s0[o00] + wt1*s0[o01] + wt2*s0[o10] + wt3*s0[o11];
            w1   = wt0*s1[o00] + wt1*s1[o01] + wt2*s1[o10] + wt3*s1[o11];
            w2   = wt0*s2[o00] + wt1*s2[o01] + wt2*s2[o10] + wt3*s2[o11];
            fbwx = wt0*s3[o00] + wt1*s3[o01] + wt2*s3[o10] + wt3*s3[o11];
            fbwy = wt0*s4[o00] + wt1*s4[o01] + wt2*s4[o10] + wt3*s4[o11];
        } else {
            const float* g1 = pib + NPIX;
            const float* g2 = pib + 2*NPIX;
            const float* pfb1 = pfb + NPIX;
            w0   = wt0*pib[idx0] + wt1*pib[idx1] + wt2*pib[idx2] + wt3*pib[idx3];
            w1   = wt0*g1[idx0]  + wt1*g1[idx1]  + wt2*g1[idx2]  + wt3*g1[idx3];
            w2   = wt0*g2[idx0]  + wt1*g2[idx1]  + wt2*g2[idx2]  + wt3*g2[idx3];
            fbwx = wt0*pfb[idx0] + wt1*pfb[idx1] + wt2*pfb[idx2] + wt3*pfb[idx3];
            fbwy = wt0*pfb1[idx0]+ wt1*pfb1[idx1]+ wt2*pfb1[idx2]+ wt3*pfb1[idx3];
        }

        // border mask
        float mx = sigmoidf_(Xp + 0.5f) * (1.f - sigmoidf_(Xp - ((float)IW - 0.5f)));
        float my = sigmoidf_(Yp + 0.5f) * (1.f - sigmoidf_(Yp - ((float)IH - 0.5f)));
        float bm = mx * my;

        float mag = fax*fax + fay*fay + fbwx*fbwx + fbwy*fbwy;
        float dfx = fax + fbwx, dfy = fay + fbwy;
        float D = dfx*dfx + dfy*dfy;
        float occ = 1.f - sigmoidf_(D - (0.01f*mag + 0.5f));
        float mask = bm * occ;

        local += (1.f - mask);                       // mask term

        float d0 = pia[p]        - w0;               // data term
        float d1 = pia[NPIX+p]   - w1;
        float d2 = pia[2*NPIX+p] - w2;
        local += fsqrt_(d0*d0 + d1*d1 + d2*d2 + 1e-5f) * mask;

        local += fsqrt_(D + 1e-5f) * mask;           // fb term

        float Bt = 0.f;                              // smoothness
        if (gw < IW-1){
            float e0 = pfa[p+1] - fax;
            float e1 = pfa[NPIX + p+1] - fay;
            Bt += e0*e0 + e1*e1;
        }
        if (gh < IH-1){
            float e0 = pfa[p+IW] - fax;
            float e1 = pfa[NPIX + p+IW] - fay;
            Bt += e0*e0 + e1*e1;
        }
        local += fsqrt_(Bt + 1e-5f);

        wout[p]          = w0;
        wout[NPIX + p]   = w1;
        wout[2*NPIX + p] = w2;
        mout[p]          = mask;
    }

    float s = block_reduce_sum(local);
    if (tid == 0) part[PA_OFF + blockIdx.x + NTX*(blockIdx.y + NTY*blockIdx.z)] = s;
}

// dirB (r4): gradient-constancy stencil from staged LDS tiles.
__global__ __launch_bounds__(256, 5)
void dirB_kernel(const float* __restrict__ img1, const float* __restrict__ img2,
                 const float* __restrict__ wimg, const float* __restrict__ maskbuf,
                 float* __restrict__ part)
{
    __shared__ float wt[3][RH][RW];
    __shared__ float at[3][RH][RW];

    const int z = blockIdx.z;
    const int dir = z & 1, b = z >> 1;
    const float* pia = ((dir == 0) ? img1 : img2) + (size_t)b*3*NPIX;
    const float* wsrc = wimg + (size_t)z*3*NPIX;
    const float* msrc = maskbuf + (size_t)z*NPIX;

    const int tw0 = blockIdx.x*TW, th0 = blockIdx.y*TH;
    const int tid = threadIdx.x;
    float local = 0.f;

    for (int i = tid; i < 3*RH*RW; i += 256){
        int c = i / (RH*RW);
        int rem = i - c*(RH*RW);
        int r = rem / RW, cc = rem - r*RW;
        int gy = th0 + r - 2;
        int gx = tw0 + cc - 2;
        float va = 0.f, vw = 0.f;
        if (gy >= 0 && gy < IH && gx >= 0 && gx < IW){
            size_t q = (size_t)c*NPIX + gy*IW + gx;
            va = pia[q];
            vw = wsrc[q];
        }
        at[c][r][cc] = va;
        wt[c][r][cc] = vw;
    }
    __syncthreads();

    const float K0 = -1.f/12.f, K1 = 2.f/3.f, K3 = -2.f/3.f, K4 = 1.f/12.f;
    #pragma unroll
    for (int it = 0; it < NITER_A; ++it){
        int i = tid + it*256;
        int hh = i >> 6, ww = i & 63;
        int p = (th0 + hh)*IW + (tw0 + ww);
        int lh = hh + 2, lw = ww + 2;
        float Ct = 0.f;
        #pragma unroll
        for (int c = 0; c < 3; ++c){
            float gxa = K0*at[c][lh][lw-2] + K1*at[c][lh][lw-1]
                      + K3*at[c][lh][lw+1] + K4*at[c][lh][lw+2];
            float gxw = K0*wt[c][lh][lw-2] + K1*wt[c][lh][lw-1]
                      + K3*wt[c][lh][lw+1] + K4*wt[c][lh][lw+2];
            float d = gxa - gxw; Ct += d*d;
            float gya = K0*at[c][lh-2][lw] + K1*at[c][lh-1][lw]
                      + K3*at[c][lh+1][lw] + K4*at[c][lh+2][lw];
            float gyw = K0*wt[c][lh-2][lw] + K1*wt[c][lh-1][lw]
                      + K3*wt[c][lh+1][lw] + K4*wt[c][lh+2][lw];
            d = gya - gyw; Ct += d*d;
        }
        local += fsqrt_(Ct + 1e-5f) * msrc[p];
    }

    float s = block_reduce_sum(local);
    if (tid == 0) part[PB_OFF + blockIdx.x + NTX*(blockIdx.y + NTY*blockIdx.z)] = s;
}

__global__ __launch_bounds__(256)
void finalize_kernel(const float* __restrict__ part, float* __restrict__ out)
{
    float e = 0.f, ent = 0.f, epe = 0.f;
    for (int i = threadIdx.x; i < 2*NB_DIR; i += 256) e += part[i];
    for (int i = threadIdx.x; i < NB_FLOW; i += 256){
        ent += part[ENT_OFF + i];
        epe += part[EPE_OFF + i];
    }
    e   = block_reduce_sum(e);
    ent = block_reduce_sum(ent);
    epe = block_reduce_sum(epe);
    if (threadIdx.x == 0){
        out[0] = e / (float)BATCH - ent / (2.f * (float)BATCH);
        out[1] = epe / ((float)BATCH * (float)NPIX);
    }
}

extern "C" void kernel_launch(void* const* d_in, const int* in_sizes, int n_in,
                              void* d_out, int out_size, void* d_ws, size_t ws_size,
                              hipStream_t stream)
{
    const float* meanf    = (const float*)d_in[0];
    const float* log_varf = (const float*)d_in[1];
    const float* meanb    = (const float*)d_in[2];
    const float* log_varb = (const float*)d_in[3];
    const float* img1     = (const float*)d_in[4];
    const float* img2     = (const float*)d_in[5];
    const float* target   = (const float*)d_in[6];
    const float* noise_f  = (const float*)d_in[7];
    const float* noise_b  = (const float*)d_in[8];

    float* ws    = (float*)d_ws;
    float* part  = ws;                          // PART_FLOATS
    float* flowf = ws + PART_FLOATS;            // 2*BN (planar)
    float* flowb = flowf + 2*(size_t)BN;        // 2*BN
    float* wimg  = flowb + 2*(size_t)BN;        // NZ*3*NPIX
    float* maskb = wimg + (size_t)NZ*3*NPIX;    // NZ*NPIX

    const int threads = 256;

    flows_kernel<<<NB_FLOW, threads, 0, stream>>>(meanf, log_varf, meanb, log_varb,
                                                  target, noise_f, noise_b,
                                                  flowf, flowb, part);

    dim3 grid(NTX, NTY, NZ);
    dirA_kernel<<<grid, threads, 0, stream>>>(flowf, flowb, img1, img2,
                                              wimg, maskb, part);
    dirB_kernel<<<grid, threads, 0, stream>>>(img1, img2, wimg, maskb, part);

    finalize_kernel<<<1, threads, 0, stream>>>(part, (float*)d_out);
}

// Round 11
// 243.213 us; speedup vs baseline: 1.0266x; 1.0266x over previous
//
// Round 11: r9 (best, 241.15 us) with ONE change — the LDS-vs-global fallback
// branch is made WAVE-UNIFORM: if (__all(inwin)) pure-LDS else whole-wave
// global gather. Per-lane divergence previously made mixed waves execute BOTH
// full paths (20 ds_read + 25 global + both address streams). Global path
// reads the same memory the LDS copy came from -> bitwise-identical output.
// dirB/flows/finalize unchanged (r4).
#include <hip/hip_runtime.h>
#include <math.h>

#define BATCH 8
#define IH 384
#define IW 512
#define NPIX (IH*IW)          // 196608
#define BN (BATCH*NPIX)       // 1572864

#define TW 64
#define TH 16
#define RW (TW+4)             // 68
#define RH (TH+4)             // 20
#define NTX (IW/TW)           // 8
#define NTY (IH/TH)           // 24
#define NZ  (BATCH*2)         // 16
#define NB_DIR (NTX*NTY*NZ)   // 3072

// staging window: tile + halo (x:8, y:4); 5 channels (img_b x3, flow_b x2).
// wave-uniform window test with exact whole-wave global fallback.
#define HSX 8
#define HSY 4
#define SH (TH+2*HSY)         // 24
#define SW (TW+2*HSX)         // 80
#define SF4 (SW/4)            // 20
#define NCH 5

#define NITER_A 4             // 1024/256

#define NB_FLOW 1536
#define PA_OFF 0
#define PB_OFF NB_DIR                  // 3072
#define ENT_OFF (2*NB_DIR)             // 6144
#define EPE_OFF (ENT_OFF + NB_FLOW)    // 7680
#define PART_FLOATS 16384

__device__ __forceinline__ float frcp_(float x){ return __builtin_amdgcn_rcpf(x); }
__device__ __forceinline__ float fsqrt_(float x){ return __builtin_amdgcn_sqrtf(x); }
__device__ __forceinline__ float sigmoidf_(float x){ return frcp_(1.0f + __expf(-x)); }

__device__ __forceinline__ float block_reduce_sum(float v){
    __shared__ float s[8];
    #pragma unroll
    for (int off=32; off>0; off>>=1) v += __shfl_down(v, off);
    int lane = threadIdx.x & 63, wid = threadIdx.x >> 6;
    if (lane==0) s[wid] = v;
    __syncthreads();
    float t = 0.f;
    if (wid==0){
        int nw = (blockDim.x+63)>>6;
        t = (lane < nw) ? s[lane] : 0.f;
        #pragma unroll
        for (int off=4; off>0; off>>=1) t += __shfl_down(t, off);
    }
    __syncthreads();
    return t;
}

// Kernel 1 (r4): flows = mean + exp(lv/2)*noise, PLANAR; entropy+epe partials.
__global__ __launch_bounds__(256)
void flows_kernel(const float* __restrict__ meanf, const float* __restrict__ log_varf,
                  const float* __restrict__ meanb, const float* __restrict__ log_varb,
                  const float* __restrict__ target,
                  const float* __restrict__ noise_f, const float* __restrict__ noise_b,
                  float* __restrict__ flowf, float* __restrict__ flowb,
                  float* __restrict__ part)
{
    int t = blockIdx.x*blockDim.x + threadIdx.x;
    if (t < NB_DIR) part[PB_OFF + t] = 0.f;
    const int NP4 = NPIX/4;
    int b = t / NP4, p4 = t - b*NP4;
    size_t i0 = ((size_t)b*2*NPIX)/4 + p4;
    size_t i1 = i0 + NPIX/4;

    const float4* mf = (const float4*)meanf;  const float4* lf = (const float4*)log_varf;
    const float4* mb = (const float4*)meanb;  const float4* lb = (const float4*)log_varb;
    const float4* nf = (const float4*)noise_f; const float4* nb = (const float4*)noise_b;
    const float4* tg = (const float4*)target;
    float4* ff = (float4*)flowf; float4* fbp = (float4*)flowb;

    float4 lf0 = lf[i0], lf1 = lf[i1], lb0 = lb[i0], lb1 = lb[i1];
    float4 mf0 = mf[i0], mf1 = mf[i1], mb0 = mb[i0], mb1 = mb[i1];
    float4 nf0 = nf[i0], nf1 = nf[i1], nb0 = nb[i0], nb1 = nb[i1];

    float4 o;
    o.x = mf0.x + __expf(0.5f*lf0.x)*nf0.x; o.y = mf0.y + __expf(0.5f*lf0.y)*nf0.y;
    o.z = mf0.z + __expf(0.5f*lf0.z)*nf0.z; o.w = mf0.w + __expf(0.5f*lf0.w)*nf0.w;
    ff[i0] = o;
    o.x = mf1.x + __expf(0.5f*lf1.x)*nf1.x; o.y = mf1.y + __expf(0.5f*lf1.y)*nf1.y;
    o.z = mf1.z + __expf(0.5f*lf1.z)*nf1.z; o.w = mf1.w + __expf(0.5f*lf1.w)*nf1.w;
    ff[i1] = o;
    o.x = mb0.x + __expf(0.5f*lb0.x)*nb0.x; o.y = mb0.y + __expf(0.5f*lb0.y)*nb0.y;
    o.z = mb0.z + __expf(0.5f*lb0.z)*nb0.z; o.w = mb0.w + __expf(0.5f*lb0.w)*nb0.w;
    fbp[i0] = o;
    o.x = mb1.x + __expf(0.5f*lb1.x)*nb1.x; o.y = mb1.y + __expf(0.5f*lb1.y)*nb1.y;
    o.z = mb1.z + __expf(0.5f*lb1.z)*nb1.z; o.w = mb1.w + __expf(0.5f*lb1.w)*nb1.w;
    fbp[i1] = o;

    float ent = (lf0.x+lf0.y+lf0.z+lf0.w) + (lf1.x+lf1.y+lf1.z+lf1.w)
              + (lb0.x+lb0.y+lb0.z+lb0.w) + (lb1.x+lb1.y+lb1.z+lb1.w);

    float4 t0 = tg[i0], t1 = tg[i1];
    float d0, d1, epe = 0.f;
    d0 = mf0.x - t0.x; d1 = mf1.x - t1.x; epe += fsqrt_(d0*d0 + d1*d1);
    d0 = mf0.y - t0.y; d1 = mf1.y - t1.y; epe += fsqrt_(d0*d0 + d1*d1);
    d0 = mf0.z - t0.z; d1 = mf1.z - t1.z; epe += fsqrt_(d0*d0 + d1*d1);
    d0 = mf0.w - t0.w; d1 = mf1.w - t1.w; epe += fsqrt_(d0*d0 + d1*d1);

    float s = block_reduce_sum(ent);
    if (threadIdx.x == 0) part[ENT_OFF + blockIdx.x] = s;
    float s2 = block_reduce_sum(epe);
    if (threadIdx.x == 0) part[EPE_OFF + blockIdx.x] = s2;
}

// ---------------------------------------------------------------------------
// dirA: r9 semantics; img_b (3ch) + flow_b (2ch) staged in one LDS window;
// wave-uniform LDS-vs-global branch.
// ---------------------------------------------------------------------------
__global__ __launch_bounds__(256, 4)
void dirA_kernel(const float* __restrict__ flowf, const float* __restrict__ flowb,
                 const float* __restrict__ img1, const float* __restrict__ img2,
                 float* __restrict__ wimg, float* __restrict__ maskbuf,
                 float* __restrict__ part)
{
    __shared__ float sib[NCH][SH][SW];   // ch0-2: img_b, ch3-4: flow_b (0 outside)

    const int z = blockIdx.z;
    const int dir = z & 1, b = z >> 1;
    const float *pfa, *pfb, *pia, *pib;
    if (dir == 0){ pfa = flowf; pfb = flowb; pia = img1; pib = img2; }
    else         { pfa = flowb; pfb = flowf; pia = img2; pib = img1; }
    pfa += (size_t)b*2*NPIX; pfb += (size_t)b*2*NPIX;
    pia += (size_t)b*3*NPIX; pib += (size_t)b*3*NPIX;

    float* wout = wimg + (size_t)z*3*NPIX;
    float* mout = maskbuf + (size_t)z*NPIX;

    const int tw0 = blockIdx.x*TW, th0 = blockIdx.y*TH;
    const int tid = threadIdx.x;
    float local = 0.f;

    // ---- stage img_b + flow_b window (float4; HSX%4==0 so no straddle) ----
    for (int i = tid; i < NCH*SH*SF4; i += 256){
        int c = i / (SH*SF4);
        int rem = i - c*(SH*SF4);
        int r = rem / SF4, c4 = rem - r*SF4;
        int gy = th0 - HSY + r;
        int gx = tw0 - HSX + 4*c4;
        float4 v = make_float4(0.f, 0.f, 0.f, 0.f);
        if (gy >= 0 && gy < IH && gx >= 0 && gx < IW){
            const float* src = (c < 3) ? (pib + (size_t)c*NPIX)
                                       : (pfb + (size_t)(c-3)*NPIX);
            v = *(const float4*)(src + gy*IW + gx);
        }
        *(float4*)&sib[c][r][4*c4] = v;
    }

    // ---- flow_a preload ----
    float rfax[NITER_A], rfay[NITER_A];
    #pragma unroll
    for (int it = 0; it < NITER_A; ++it){
        int i = tid + it*256;
        int hh = i >> 6, ww = i & 63;
        int p = (th0 + hh)*IW + (tw0 + ww);
        rfax[it] = pfa[p];
        rfay[it] = pfa[NPIX + p];
    }
    __syncthreads();

    // ---- warp + terms ----
    #pragma unroll
    for (int it = 0; it < NITER_A; ++it){
        int i = tid + it*256;
        int hh = i >> 6, ww = i & 63;
        int gh = th0 + hh, gw = tw0 + ww;
        int p = gh*IW + gw;
        float fax = rfax[it], fay = rfay[it];
        float Xp = (float)gw + fax;
        float Yp = (float)gh + fay;

        float x0f = floorf(Xp), y0f = floorf(Yp);
        float wx1 = Xp - x0f, wy1 = Yp - y0f;
        float wx0 = 1.f - wx1, wy0 = 1.f - wy1;

        float x1f = x0f + 1.f, y1f = y0f + 1.f;
        bool vx0 = (x0f >= 0.f) && (x0f <= (float)(IW-1));
        bool vx1 = (x1f >= 0.f) && (x1f <= (float)(IW-1));
        bool vy0 = (y0f >= 0.f) && (y0f <= (float)(IH-1));
        bool vy1 = (y1f >= 0.f) && (y1f <= (float)(IH-1));
        float xc0 = fminf(fmaxf(x0f, 0.f), (float)(IW-1));
        float xc1 = fminf(fmaxf(x1f, 0.f), (float)(IW-1));
        float yc0 = fminf(fmaxf(y0f, 0.f), (float)(IH-1));
        float yc1 = fminf(fmaxf(y1f, 0.f), (float)(IH-1));
        int ix0 = (int)xc0, ix1 = (int)xc1, iy0 = (int)yc0, iy1 = (int)yc1;
        int idx0 = iy0*IW + ix0, idx1 = iy0*IW + ix1;
        int idx2 = iy1*IW + ix0, idx3 = iy1*IW + ix1;
        float wt0 = (vx0 && vy0) ? wx0*wy0 : 0.f;
        float wt1 = (vx1 && vy0) ? wx1*wy0 : 0.f;
        float wt2 = (vx0 && vy1) ? wx0*wy1 : 0.f;
        float wt3 = (vx1 && vy1) ? wx1*wy1 : 0.f;

        // warp img_b (3 ch) + flow_b (2 ch): wave-uniform LDS vs global path.
        // Global path reads the identical memory the LDS copy came from, so
        // both paths give bitwise-equal values for every lane.
        float w0, w1, w2, fbwx, fbwy;
        int lx0 = ix0 - (tw0 - HSX), ly0 = iy0 - (th0 - HSY);
        int lx1 = ix1 - (tw0 - HSX), ly1 = iy1 - (th0 - HSY);
        bool inwin = (lx0 >= 0) && (lx1 < SW) && (ly0 >= 0) && (ly1 < SH);
        if (__all(inwin)){
            int o00 = ly0*SW + lx0, o01 = ly0*SW + lx1;
            int o10 = ly1*SW + lx0, o11 = ly1*SW + lx1;
            const float* s0 = &sib[0][0][0];
            const float* s1 = s0 + SH*SW;
            const float* s2 = s1 + SH*SW;
            const float* s3 = s2 + SH*SW;
            const float* s4 = s3 + SH*SW;
            w0   = wt0*s0[o00] + wt1*s0[o01] + wt2*s0[o10] + wt3*s0[o11];
            w1   = wt0*s1[o00] + wt1*s1[o01] + wt2*s1[o10] + wt3*s1[o11];
            w2   = wt0*s2[o00] + wt1*s2[o01] + wt2*s2[o10] + wt3*s2[o11];
            fbwx = wt0*s3[o00] + wt1*s3[o01] + wt2*s3[o10] + wt3*s3[o11];
            fbwy = wt0*s4[o00] + wt1*s4[o01] + wt2*s4[o10] + wt3*s4[o11];
        } else {
            const float* g1 = pib + NPIX;
            const float* g2 = pib + 2*NPIX;
            const float* pfb1 = pfb + NPIX;
            w0   = wt0*pib[idx0] + wt1*pib[idx1] + wt2*pib[idx2] + wt3*pib[idx3];
            w1   = wt0*g1[idx0]  + wt1*g1[idx1]  + wt2*g1[idx2]  + wt3*g1[idx3];
            w2   = wt0*g2[idx0]  + wt1*g2[idx1]  + wt2*g2[idx2]  + wt3*g2[idx3];
            fbwx = wt0*pfb[idx0] + wt1*pfb[idx1] + wt2*pfb[idx2] + wt3*pfb[idx3];
            fbwy = wt0*pfb1[idx0]+ wt1*pfb1[idx1]+ wt2*pfb1[idx2]+ wt3*pfb1[idx3];
        }

        // border mask
        float mx = sigmoidf_(Xp + 0.5f) * (1.f - sigmoidf_(Xp - ((float)IW - 0.5f)));
        float my = sigmoidf_(Yp + 0.5f) * (1.f - sigmoidf_(Yp - ((float)IH - 0.5f)));
        float bm = mx * my;

        float mag = fax*fax + fay*fay + fbwx*fbwx + fbwy*fbwy;
        float dfx = fax + fbwx, dfy = fay + fbwy;
        float D = dfx*dfx + dfy*dfy;
        float occ = 1.f - sigmoidf_(D - (0.01f*mag + 0.5f));
        float mask = bm * occ;

        local += (1.f - mask);                       // mask term

        float d0 = pia[p]        - w0;               // data term
        float d1 = pia[NPIX+p]   - w1;
        float d2 = pia[2*NPIX+p] - w2;
        local += fsqrt_(d0*d0 + d1*d1 + d2*d2 + 1e-5f) * mask;

        local += fsqrt_(D + 1e-5f) * mask;           // fb term

        float Bt = 0.f;                              // smoothness
        if (gw < IW-1){
            float e0 = pfa[p+1] - fax;
            float e1 = pfa[NPIX + p+1] - fay;
            Bt += e0*e0 + e1*e1;
        }
        if (gh < IH-1){
            float e0 = pfa[p+IW] - fax;
            float e1 = pfa[NPIX + p+IW] - fay;
            Bt += e0*e0 + e1*e1;
        }
        local += fsqrt_(Bt + 1e-5f);

        wout[p]          = w0;
        wout[NPIX + p]   = w1;
        wout[2*NPIX + p] = w2;
        mout[p]          = mask;
    }

    float s = block_reduce_sum(local);
    if (tid == 0) part[PA_OFF + blockIdx.x + NTX*(blockIdx.y + NTY*blockIdx.z)] = s;
}

// dirB (r4): gradient-constancy stencil from staged LDS tiles.
__global__ __launch_bounds__(256, 5)
void dirB_kernel(const float* __restrict__ img1, const float* __restrict__ img2,
                 const float* __restrict__ wimg, const float* __restrict__ maskbuf,
                 float* __restrict__ part)
{
    __shared__ float wt[3][RH][RW];
    __shared__ float at[3][RH][RW];

    const int z = blockIdx.z;
    const int dir = z & 1, b = z >> 1;
    const float* pia = ((dir == 0) ? img1 : img2) + (size_t)b*3*NPIX;
    const float* wsrc = wimg + (size_t)z*3*NPIX;
    const float* msrc = maskbuf + (size_t)z*NPIX;

    const int tw0 = blockIdx.x*TW, th0 = blockIdx.y*TH;
    const int tid = threadIdx.x;
    float local = 0.f;

    for (int i = tid; i < 3*RH*RW; i += 256){
        int c = i / (RH*RW);
        int rem = i - c*(RH*RW);
        int r = rem / RW, cc = rem - r*RW;
        int gy = th0 + r - 2;
        int gx = tw0 + cc - 2;
        float va = 0.f, vw = 0.f;
        if (gy >= 0 && gy < IH && gx >= 0 && gx < IW){
            size_t q = (size_t)c*NPIX + gy*IW + gx;
            va = pia[q];
            vw = wsrc[q];
        }
        at[c][r][cc] = va;
        wt[c][r][cc] = vw;
    }
    __syncthreads();

    const float K0 = -1.f/12.f, K1 = 2.f/3.f, K3 = -2.f/3.f, K4 = 1.f/12.f;
    #pragma unroll
    for (int it = 0; it < NITER_A; ++it){
        int i = tid + it*256;
        int hh = i >> 6, ww = i & 63;
        int p = (th0 + hh)*IW + (tw0 + ww);
        int lh = hh + 2, lw = ww + 2;
        float Ct = 0.f;
        #pragma unroll
        for (int c = 0; c < 3; ++c){
            float gxa = K0*at[c][lh][lw-2] + K1*at[c][lh][lw-1]
                      + K3*at[c][lh][lw+1] + K4*at[c][lh][lw+2];
            float gxw = K0*wt[c][lh][lw-2] + K1*wt[c][lh][lw-1]
                      + K3*wt[c][lh][lw+1] + K4*wt[c][lh][lw+2];
            float d = gxa - gxw; Ct += d*d;
            float gya = K0*at[c][lh-2][lw] + K1*at[c][lh-1][lw]
                      + K3*at[c][lh+1][lw] + K4*at[c][lh+2][lw];
            float gyw = K0*wt[c][lh-2][lw] + K1*wt[c][lh-1][lw]
                      + K3*wt[c][lh+1][lw] + K4*wt[c][lh+2][lw];
            d = gya - gyw; Ct += d*d;
        }
        local += fsqrt_(Ct + 1e-5f) * msrc[p];
    }

    float s = block_reduce_sum(local);
    if (tid == 0) part[PB_OFF + blockIdx.x + NTX*(blockIdx.y + NTY*blockIdx.z)] = s;
}

__global__ __launch_bounds__(256)
void finalize_kernel(const float* __restrict__ part, float* __restrict__ out)
{
    float e = 0.f, ent = 0.f, epe = 0.f;
    for (int i = threadIdx.x; i < 2*NB_DIR; i += 256) e += part[i];
    for (int i = threadIdx.x; i < NB_FLOW; i += 256){
        ent += part[ENT_OFF + i];
        epe += part[EPE_OFF + i];
    }
    e   = block_reduce_sum(e);
    ent = block_reduce_sum(ent);
    epe = block_reduce_sum(epe);
    if (threadIdx.x == 0){
        out[0] = e / (float)BATCH - ent / (2.f * (float)BATCH);
        out[1] = epe / ((float)BATCH * (float)NPIX);
    }
}

extern "C" void kernel_launch(void* const* d_in, const int* in_sizes, int n_in,
                              void* d_out, int out_size, void* d_ws, size_t ws_size,
                              hipStream_t stream)
{
    const float* meanf    = (const float*)d_in[0];
    const float* log_varf = (const float*)d_in[1];
    const float* meanb    = (const float*)d_in[2];
    const float* log_varb = (const float*)d_in[3];
    const float* img1     = (const float*)d_in[4];
    const float* img2     = (const float*)d_in[5];
    const float* target   = (const float*)d_in[6];
    const float* noise_f  = (const float*)d_in[7];
    const float* noise_b  = (const float*)d_in[8];

    float* ws    = (float*)d_ws;
    float* part  = ws;                          // PART_FLOATS
    float* flowf = ws + PART_FLOATS;            // 2*BN (planar)
    float* flowb = flowf + 2*(size_t)BN;        // 2*BN
    float* wimg  = flowb + 2*(size_t)BN;        // NZ*3*NPIX
    float* maskb = wimg + (size_t)NZ*3*NPIX;    // NZ*NPIX

    const int threads = 256;

    flows_kernel<<<NB_FLOW, threads, 0, stream>>>(meanf, log_varf, meanb, log_varb,
                                                  target, noise_f, noise_b,
                                                  flowf, flowb, part);

    dim3 grid(NTX, NTY, NZ);
    dirA_kernel<<<grid, threads, 0, stream>>>(flowf, flowb, img1, img2,
                                              wimg, maskb, part);
    dirB_kernel<<<grid, threads, 0, stream>>>(img1, img2, wimg, maskb, part);

    finalize_kernel<<<1, threads, 0, stream>>>(part, (float*)d_out);
}

// Round 12
// 223.075 us; speedup vs baseline: 1.1193x; 1.0903x over previous
//
// Round 12: r9 (best, 241.15us; dirA=55.8) with ONE change — 512-thread blocks
// for dirA and dirB (same 64x16 tile, half the per-thread iterations).
// dirA: 4 resident blocks x 8 waves = 32 waves/CU (HW max), 2x the latency-
// hiding chains for this latency-bound kernel. LDS 4x38.9KB=155.6 <= 160KB.
// All per-pixel arithmetic identical to r9 (per-lane inwin branch, HSY=4).
#include <hip/hip_runtime.h>
#include <math.h>

#define BATCH 8
#define IH 384
#define IW 512
#define NPIX (IH*IW)          // 196608
#define BN (BATCH*NPIX)       // 1572864

#define TW 64
#define TH 16
#define RW (TW+4)             // 68
#define RH (TH+4)             // 20
#define NTX (IW/TW)           // 8
#define NTY (IH/TH)           // 24
#define NZ  (BATCH*2)         // 16
#define NB_DIR (NTX*NTY*NZ)   // 3072

// staging window: tile + halo (x:8, y:4); 5 channels (img_b x3, flow_b x2).
#define HSX 8
#define HSY 4
#define SH (TH+2*HSY)         // 24
#define SW (TW+2*HSX)         // 80
#define SF4 (SW/4)            // 20
#define NCH 5

#define TPB_DIR 512
#define NITER_A 2             // 1024/512

#define NB_FLOW 1536
#define PA_OFF 0
#define PB_OFF NB_DIR                  // 3072
#define ENT_OFF (2*NB_DIR)             // 6144
#define EPE_OFF (ENT_OFF + NB_FLOW)    // 7680
#define PART_FLOATS 16384

__device__ __forceinline__ float frcp_(float x){ return __builtin_amdgcn_rcpf(x); }
__device__ __forceinline__ float fsqrt_(float x){ return __builtin_amdgcn_sqrtf(x); }
__device__ __forceinline__ float sigmoidf_(float x){ return frcp_(1.0f + __expf(-x)); }

__device__ __forceinline__ float block_reduce_sum(float v){
    __shared__ float s[8];
    #pragma unroll
    for (int off=32; off>0; off>>=1) v += __shfl_down(v, off);
    int lane = threadIdx.x & 63, wid = threadIdx.x >> 6;
    if (lane==0) s[wid] = v;
    __syncthreads();
    float t = 0.f;
    if (wid==0){
        int nw = (blockDim.x+63)>>6;
        t = (lane < nw) ? s[lane] : 0.f;
        #pragma unroll
        for (int off=4; off>0; off>>=1) t += __shfl_down(t, off);
    }
    __syncthreads();
    return t;
}

// Kernel 1 (r4): flows = mean + exp(lv/2)*noise, PLANAR; entropy+epe partials.
__global__ __launch_bounds__(256)
void flows_kernel(const float* __restrict__ meanf, const float* __restrict__ log_varf,
                  const float* __restrict__ meanb, const float* __restrict__ log_varb,
                  const float* __restrict__ target,
                  const float* __restrict__ noise_f, const float* __restrict__ noise_b,
                  float* __restrict__ flowf, float* __restrict__ flowb,
                  float* __restrict__ part)
{
    int t = blockIdx.x*blockDim.x + threadIdx.x;
    if (t < NB_DIR) part[PB_OFF + t] = 0.f;
    const int NP4 = NPIX/4;
    int b = t / NP4, p4 = t - b*NP4;
    size_t i0 = ((size_t)b*2*NPIX)/4 + p4;
    size_t i1 = i0 + NPIX/4;

    const float4* mf = (const float4*)meanf;  const float4* lf = (const float4*)log_varf;
    const float4* mb = (const float4*)meanb;  const float4* lb = (const float4*)log_varb;
    const float4* nf = (const float4*)noise_f; const float4* nb = (const float4*)noise_b;
    const float4* tg = (const float4*)target;
    float4* ff = (float4*)flowf; float4* fbp = (float4*)flowb;

    float4 lf0 = lf[i0], lf1 = lf[i1], lb0 = lb[i0], lb1 = lb[i1];
    float4 mf0 = mf[i0], mf1 = mf[i1], mb0 = mb[i0], mb1 = mb[i1];
    float4 nf0 = nf[i0], nf1 = nf[i1], nb0 = nb[i0], nb1 = nb[i1];

    float4 o;
    o.x = mf0.x + __expf(0.5f*lf0.x)*nf0.x; o.y = mf0.y + __expf(0.5f*lf0.y)*nf0.y;
    o.z = mf0.z + __expf(0.5f*lf0.z)*nf0.z; o.w = mf0.w + __expf(0.5f*lf0.w)*nf0.w;
    ff[i0] = o;
    o.x = mf1.x + __expf(0.5f*lf1.x)*nf1.x; o.y = mf1.y + __expf(0.5f*lf1.y)*nf1.y;
    o.z = mf1.z + __expf(0.5f*lf1.z)*nf1.z; o.w = mf1.w + __expf(0.5f*lf1.w)*nf1.w;
    ff[i1] = o;
    o.x = mb0.x + __expf(0.5f*lb0.x)*nb0.x; o.y = mb0.y + __expf(0.5f*lb0.y)*nb0.y;
    o.z = mb0.z + __expf(0.5f*lb0.z)*nb0.z; o.w = mb0.w + __expf(0.5f*lb0.w)*nb0.w;
    fbp[i0] = o;
    o.x = mb1.x + __expf(0.5f*lb1.x)*nb1.x; o.y = mb1.y + __expf(0.5f*lb1.y)*nb1.y;
    o.z = mb1.z + __expf(0.5f*lb1.z)*nb1.z; o.w = mb1.w + __expf(0.5f*lb1.w)*nb1.w;
    fbp[i1] = o;

    float ent = (lf0.x+lf0.y+lf0.z+lf0.w) + (lf1.x+lf1.y+lf1.z+lf1.w)
              + (lb0.x+lb0.y+lb0.z+lb0.w) + (lb1.x+lb1.y+lb1.z+lb1.w);

    float4 t0 = tg[i0], t1 = tg[i1];
    float d0, d1, epe = 0.f;
    d0 = mf0.x - t0.x; d1 = mf1.x - t1.x; epe += fsqrt_(d0*d0 + d1*d1);
    d0 = mf0.y - t0.y; d1 = mf1.y - t1.y; epe += fsqrt_(d0*d0 + d1*d1);
    d0 = mf0.z - t0.z; d1 = mf1.z - t1.z; epe += fsqrt_(d0*d0 + d1*d1);
    d0 = mf0.w - t0.w; d1 = mf1.w - t1.w; epe += fsqrt_(d0*d0 + d1*d1);

    float s = block_reduce_sum(ent);
    if (threadIdx.x == 0) part[ENT_OFF + blockIdx.x] = s;
    float s2 = block_reduce_sum(epe);
    if (threadIdx.x == 0) part[EPE_OFF + blockIdx.x] = s2;
}

// ---------------------------------------------------------------------------
// dirA: r9 semantics; img_b (3ch) + flow_b (2ch) staged in one LDS window;
// 512 threads (8 waves) per block -> 32 waves/CU at 4 resident blocks.
// ---------------------------------------------------------------------------
__global__ __launch_bounds__(TPB_DIR, 8)
void dirA_kernel(const float* __restrict__ flowf, const float* __restrict__ flowb,
                 const float* __restrict__ img1, const float* __restrict__ img2,
                 float* __restrict__ wimg, float* __restrict__ maskbuf,
                 float* __restrict__ part)
{
    __shared__ float sib[NCH][SH][SW];   // ch0-2: img_b, ch3-4: flow_b (0 outside)

    const int z = blockIdx.z;
    const int dir = z & 1, b = z >> 1;
    const float *pfa, *pfb, *pia, *pib;
    if (dir == 0){ pfa = flowf; pfb = flowb; pia = img1; pib = img2; }
    else         { pfa = flowb; pfb = flowf; pia = img2; pib = img1; }
    pfa += (size_t)b*2*NPIX; pfb += (size_t)b*2*NPIX;
    pia += (size_t)b*3*NPIX; pib += (size_t)b*3*NPIX;

    float* wout = wimg + (size_t)z*3*NPIX;
    float* mout = maskbuf + (size_t)z*NPIX;

    const int tw0 = blockIdx.x*TW, th0 = blockIdx.y*TH;
    const int tid = threadIdx.x;
    float local = 0.f;

    // ---- stage img_b + flow_b window (float4; HSX%4==0 so no straddle) ----
    for (int i = tid; i < NCH*SH*SF4; i += TPB_DIR){
        int c = i / (SH*SF4);
        int rem = i - c*(SH*SF4);
        int r = rem / SF4, c4 = rem - r*SF4;
        int gy = th0 - HSY + r;
        int gx = tw0 - HSX + 4*c4;
        float4 v = make_float4(0.f, 0.f, 0.f, 0.f);
        if (gy >= 0 && gy < IH && gx >= 0 && gx < IW){
            const float* src = (c < 3) ? (pib + (size_t)c*NPIX)
                                       : (pfb + (size_t)(c-3)*NPIX);
            v = *(const float4*)(src + gy*IW + gx);
        }
        *(float4*)&sib[c][r][4*c4] = v;
    }

    // ---- flow_a preload ----
    float rfax[NITER_A], rfay[NITER_A];
    #pragma unroll
    for (int it = 0; it < NITER_A; ++it){
        int i = tid + it*TPB_DIR;
        int hh = i >> 6, ww = i & 63;
        int p = (th0 + hh)*IW + (tw0 + ww);
        rfax[it] = pfa[p];
        rfay[it] = pfa[NPIX + p];
    }
    __syncthreads();

    // ---- warp + terms ----
    #pragma unroll
    for (int it = 0; it < NITER_A; ++it){
        int i = tid + it*TPB_DIR;
        int hh = i >> 6, ww = i & 63;
        int gh = th0 + hh, gw = tw0 + ww;
        int p = gh*IW + gw;
        float fax = rfax[it], fay = rfay[it];
        float Xp = (float)gw + fax;
        float Yp = (float)gh + fay;

        float x0f = floorf(Xp), y0f = floorf(Yp);
        float wx1 = Xp - x0f, wy1 = Yp - y0f;
        float wx0 = 1.f - wx1, wy0 = 1.f - wy1;

        float x1f = x0f + 1.f, y1f = y0f + 1.f;
        bool vx0 = (x0f >= 0.f) && (x0f <= (float)(IW-1));
        bool vx1 = (x1f >= 0.f) && (x1f <= (float)(IW-1));
        bool vy0 = (y0f >= 0.f) && (y0f <= (float)(IH-1));
        bool vy1 = (y1f >= 0.f) && (y1f <= (float)(IH-1));
        float xc0 = fminf(fmaxf(x0f, 0.f), (float)(IW-1));
        float xc1 = fminf(fmaxf(x1f, 0.f), (float)(IW-1));
        float yc0 = fminf(fmaxf(y0f, 0.f), (float)(IH-1));
        float yc1 = fminf(fmaxf(y1f, 0.f), (float)(IH-1));
        int ix0 = (int)xc0, ix1 = (int)xc1, iy0 = (int)yc0, iy1 = (int)yc1;
        int idx0 = iy0*IW + ix0, idx1 = iy0*IW + ix1;
        int idx2 = iy1*IW + ix0, idx3 = iy1*IW + ix1;
        float wt0 = (vx0 && vy0) ? wx0*wy0 : 0.f;
        float wt1 = (vx1 && vy0) ? wx1*wy0 : 0.f;
        float wt2 = (vx0 && vy1) ? wx0*wy1 : 0.f;
        float wt3 = (vx1 && vy1) ? wx1*wy1 : 0.f;

        // warp img_b (3 ch) + flow_b (2 ch): LDS window if all taps inside
        float w0, w1, w2, fbwx, fbwy;
        int lx0 = ix0 - (tw0 - HSX), ly0 = iy0 - (th0 - HSY);
        int lx1 = ix1 - (tw0 - HSX), ly1 = iy1 - (th0 - HSY);
        bool inwin = (lx0 >= 0) && (lx1 < SW) && (ly0 >= 0) && (ly1 < SH);
        if (inwin){
            int o00 = ly0*SW + lx0, o01 = ly0*SW + lx1;
            int o10 = ly1*SW + lx0, o11 = ly1*SW + lx1;
            const float* s0 = &sib[0][0][0];
            const float* s1 = s0 + SH*SW;
            const float* s2 = s1 + SH*SW;
            const float* s3 = s2 + SH*SW;
            const float* s4 = s3 + SH*SW;
            w0   = wt0*s0[o00] + wt1*s0[o01] + wt2*s0[o10] + wt3*s0[o11];
            w1   = wt0*s1[o00] + wt1*s1[o01] + wt2*s1[o10] + wt3*s1[o11];
            w2   = wt0*s2[o00] + wt1*s2[o01] + wt2*s2[o10] + wt3*s2[o11];
            fbwx = wt0*s3[o00] + wt1*s3[o01] + wt2*s3[o10] + wt3*s3[o11];
            fbwy = wt0*s4[o00] + wt1*s4[o01] + wt2*s4[o10] + wt3*s4[o11];
        } else {
            const float* g1 = pib + NPIX;
            const float* g2 = pib + 2*NPIX;
            const float* pfb1 = pfb + NPIX;
            w0   = wt0*pib[idx0] + wt1*pib[idx1] + wt2*pib[idx2] + wt3*pib[idx3];
            w1   = wt0*g1[idx0]  + wt1*g1[idx1]  + wt2*g1[idx2]  + wt3*g1[idx3];
            w2   = wt0*g2[idx0]  + wt1*g2[idx1]  + wt2*g2[idx2]  + wt3*g2[idx3];
            fbwx = wt0*pfb[idx0] + wt1*pfb[idx1] + wt2*pfb[idx2] + wt3*pfb[idx3];
            fbwy = wt0*pfb1[idx0]+ wt1*pfb1[idx1]+ wt2*pfb1[idx2]+ wt3*pfb1[idx3];
        }

        // border mask
        float mx = sigmoidf_(Xp + 0.5f) * (1.f - sigmoidf_(Xp - ((float)IW - 0.5f)));
        float my = sigmoidf_(Yp + 0.5f) * (1.f - sigmoidf_(Yp - ((float)IH - 0.5f)));
        float bm = mx * my;

        float mag = fax*fax + fay*fay + fbwx*fbwx + fbwy*fbwy;
        float dfx = fax + fbwx, dfy = fay + fbwy;
        float D = dfx*dfx + dfy*dfy;
        float occ = 1.f - sigmoidf_(D - (0.01f*mag + 0.5f));
        float mask = bm * occ;

        local += (1.f - mask);                       // mask term

        float d0 = pia[p]        - w0;               // data term
        float d1 = pia[NPIX+p]   - w1;
        float d2 = pia[2*NPIX+p] - w2;
        local += fsqrt_(d0*d0 + d1*d1 + d2*d2 + 1e-5f) * mask;

        local += fsqrt_(D + 1e-5f) * mask;           // fb term

        float Bt = 0.f;                              // smoothness
        if (gw < IW-1){
            float e0 = pfa[p+1] - fax;
            float e1 = pfa[NPIX + p+1] - fay;
            Bt += e0*e0 + e1*e1;
        }
        if (gh < IH-1){
            float e0 = pfa[p+IW] - fax;
            float e1 = pfa[NPIX + p+IW] - fay;
            Bt += e0*e0 + e1*e1;
        }
        local += fsqrt_(Bt + 1e-5f);

        wout[p]          = w0;
        wout[NPIX + p]   = w1;
        wout[2*NPIX + p] = w2;
        mout[p]          = mask;
    }

    float s = block_reduce_sum(local);
    if (tid == 0) part[PA_OFF + blockIdx.x + NTX*(blockIdx.y + NTY*blockIdx.z)] = s;
}

// dirB: gradient-constancy stencil from staged LDS tiles; 512 threads.
__global__ __launch_bounds__(TPB_DIR, 8)
void dirB_kernel(const float* __restrict__ img1, const float* __restrict__ img2,
                 const float* __restrict__ wimg, const float* __restrict__ maskbuf,
                 float* __restrict__ part)
{
    __shared__ float wt[3][RH][RW];
    __shared__ float at[3][RH][RW];

    const int z = blockIdx.z;
    const int dir = z & 1, b = z >> 1;
    const float* pia = ((dir == 0) ? img1 : img2) + (size_t)b*3*NPIX;
    const float* wsrc = wimg + (size_t)z*3*NPIX;
    const float* msrc = maskbuf + (size_t)z*NPIX;

    const int tw0 = blockIdx.x*TW, th0 = blockIdx.y*TH;
    const int tid = threadIdx.x;
    float local = 0.f;

    for (int i = tid; i < 3*RH*RW; i += TPB_DIR){
        int c = i / (RH*RW);
        int rem = i - c*(RH*RW);
        int r = rem / RW, cc = rem - r*RW;
        int gy = th0 + r - 2;
        int gx = tw0 + cc - 2;
        float va = 0.f, vw = 0.f;
        if (gy >= 0 && gy < IH && gx >= 0 && gx < IW){
            size_t q = (size_t)c*NPIX + gy*IW + gx;
            va = pia[q];
            vw = wsrc[q];
        }
        at[c][r][cc] = va;
        wt[c][r][cc] = vw;
    }
    __syncthreads();

    const float K0 = -1.f/12.f, K1 = 2.f/3.f, K3 = -2.f/3.f, K4 = 1.f/12.f;
    #pragma unroll
    for (int it = 0; it < NITER_A; ++it){
        int i = tid + it*TPB_DIR;
        int hh = i >> 6, ww = i & 63;
        int p = (th0 + hh)*IW + (tw0 + ww);
        int lh = hh + 2, lw = ww + 2;
        float Ct = 0.f;
        #pragma unroll
        for (int c = 0; c < 3; ++c){
            float gxa = K0*at[c][lh][lw-2] + K1*at[c][lh][lw-1]
                      + K3*at[c][lh][lw+1] + K4*at[c][lh][lw+2];
            float gxw = K0*wt[c][lh][lw-2] + K1*wt[c][lh][lw-1]
                      + K3*wt[c][lh][lw+1] + K4*wt[c][lh][lw+2];
            float d = gxa - gxw; Ct += d*d;
            float gya = K0*at[c][lh-2][lw] + K1*at[c][lh-1][lw]
                      + K3*at[c][lh+1][lw] + K4*at[c][lh+2][lw];
            float gyw = K0*wt[c][lh-2][lw] + K1*wt[c][lh-1][lw]
                      + K3*wt[c][lh+1][lw] + K4*wt[c][lh+2][lw];
            d = gya - gyw; Ct += d*d;
        }
        local += fsqrt_(Ct + 1e-5f) * msrc[p];
    }

    float s = block_reduce_sum(local);
    if (tid == 0) part[PB_OFF + blockIdx.x + NTX*(blockIdx.y + NTY*blockIdx.z)] = s;
}

__global__ __launch_bounds__(256)
void finalize_kernel(const float* __restrict__ part, float* __restrict__ out)
{
    float e = 0.f, ent = 0.f, epe = 0.f;
    for (int i = threadIdx.x; i < 2*NB_DIR; i += 256) e += part[i];
    for (int i = threadIdx.x; i < NB_FLOW; i += 256){
        ent += part[ENT_OFF + i];
        epe += part[EPE_OFF + i];
    }
    e   = block_reduce_sum(e);
    ent = block_reduce_sum(ent);
    epe = block_reduce_sum(epe);
    if (threadIdx.x == 0){
        out[0] = e / (float)BATCH - ent / (2.f * (float)BATCH);
        out[1] = epe / ((float)BATCH * (float)NPIX);
    }
}

extern "C" void kernel_launch(void* const* d_in, const int* in_sizes, int n_in,
                              void* d_out, int out_size, void* d_ws, size_t ws_size,
                              hipStream_t stream)
{
    const float* meanf    = (const float*)d_in[0];
    const float* log_varf = (const float*)d_in[1];
    const float* meanb    = (const float*)d_in[2];
    const float* log_varb = (const float*)d_in[3];
    const float* img1     = (const float*)d_in[4];
    const float* img2     = (const float*)d_in[5];
    const float* target   = (const float*)d_in[6];
    const float* noise_f  = (const float*)d_in[7];
    const float* noise_b  = (const float*)d_in[8];

    float* ws    = (float*)d_ws;
    float* part  = ws;                          // PART_FLOATS
    float* flowf = ws + PART_FLOATS;            // 2*BN (planar)
    float* flowb = flowf + 2*(size_t)BN;        // 2*BN
    float* wimg  = flowb + 2*(size_t)BN;        // NZ*3*NPIX
    float* maskb = wimg + (size_t)NZ*3*NPIX;    // NZ*NPIX

    flows_kernel<<<NB_FLOW, 256, 0, stream>>>(meanf, log_varf, meanb, log_varb,
                                              target, noise_f, noise_b,
                                              flowf, flowb, part);

    dim3 grid(NTX, NTY, NZ);
    dirA_kernel<<<grid, TPB_DIR, 0, stream>>>(flowf, flowb, img1, img2,
                                              wimg, maskb, part);
    dirB_kernel<<<grid, TPB_DIR, 0, stream>>>(img1, img2, wimg, maskb, part);

    finalize_kernel<<<1, 256, 0, stream>>>(part, (float*)d_out);
}